// Round 9
// baseline (441.779 us; speedup 1.0000x reference)
//
#include <hip/hip_runtime.h>
#include <stdint.h>

#define N_ROWS 65536
#define D_IN   1024
#define NBIT   64
#define LN_EPS 1e-5f

typedef __attribute__((ext_vector_type(8)))  _Float16 f16x8;
typedef __attribute__((ext_vector_type(4)))  float f32x4;
typedef __attribute__((ext_vector_type(16))) float f32x16;

__device__ __forceinline__ void gload_lds16(const void* g, void* l) {
    __builtin_amdgcn_global_load_lds(
        (const __attribute__((address_space(1))) uint32_t*)g,
        (__attribute__((address_space(3))) uint32_t*)l, 16, 0, 0);
}

__device__ __forceinline__ f32x16 mfma32(f16x8 a, f16x8 b, f32x16 c) {
    return __builtin_amdgcn_mfma_f32_32x32x16_f16(a, b, c, 0, 0, 0);
}

// ---------------- kernel 0: prep split-W fragments + per-bit constants ----------------
// K-split 32x32x16 fragment layout, BK=64 chunks (16 chunks), kh-subtiled:
//   bit = nt*32 + (lane&31),  k = c*64 + kh*32 + t*16 + (lane>>5)*8 + j
//   idx = c*4096 + kh*2048 + t*1024 + nt*512 + lane*8 + j   (shorts, per hi/lo array)
// whi = fp16(gw); wlo = fp16((gw - whi)*2048)  [exact split, lo scaled to stay normal]
__global__ void prep_kernel(const float* __restrict__ W, const float* __restrict__ bias,
                            const float* __restrict__ g1, const float* __restrict__ b1,
                            _Float16* __restrict__ whi, _Float16* __restrict__ wlo,
                            float* __restrict__ u, float* __restrict__ v) {
    int bit = blockIdx.x;            // 0..63
    int t   = threadIdx.x;           // 0..255
    int nt  = bit >> 5, col = bit & 31;
    float su = 0.f, sv = 0.f;
    for (int d = t; d < D_IN; d += 256) {
        float w  = W[bit * D_IN + d];
        float gw = w * g1[d];
        su += gw;
        sv += w * b1[d];
        int c   = d >> 6, w6 = d & 63;
        int kh  = w6 >> 5, tt = (w6 >> 4) & 1, hi8 = (w6 >> 3) & 1, j = d & 7;
        int lane = col + 32 * hi8;
        size_t idx = (size_t)c * 4096 + kh * 2048 + tt * 1024 + nt * 512 + lane * 8 + j;
        _Float16 h = (_Float16)gw;
        whi[idx] = h;
        wlo[idx] = (_Float16)((gw - (float)h) * 2048.0f);
    }
    __shared__ float s1[256], s2[256];
    s1[t] = su; s2[t] = sv;
    __syncthreads();
    for (int off = 128; off > 0; off >>= 1) {
        if (t < off) { s1[t] += s1[t + off]; s2[t] += s2[t + off]; }
        __syncthreads();
    }
    if (t == 0) { u[bit] = s1[0]; v[bit] = s2[0] + bias[bit]; }
}

// ---------------- kernel 1: fused LN1 + K-split 32x32 GEMM + LN2 + partials ----------------
// 4 waves/block: waves {0,1} = K-half 0 for rows [0,32)/[32,64); waves {2,3} = K-half 1.
// 64 rows/block, grid 1024 -> 4 blocks/CU (16 waves/CU, 4/SIMD): doubles occupancy so
// other blocks' compute hides each block's post-barrier HBM latency hole.
// LDS: W chunk 16 KiB double-buffered (32 KiB) + 1 KiB stat exchange = 33 KiB/block.
__global__ void __launch_bounds__(256, 4) main_kernel(
        const float* __restrict__ X,
        const _Float16* __restrict__ whi, const _Float16* __restrict__ wlo,
        const float* __restrict__ u, const float* __restrict__ v,
        const float* __restrict__ g2, const float* __restrict__ b2,
        float* __restrict__ L, float* __restrict__ P) {
    __shared__ _Float16 lw[2][8192];   // per buf: hi [0,4096) | lo [4096,8192) shorts
    __shared__ float s_ss[2][128];     // cross-wave sum/sumsq exchange
    int tid  = threadIdx.x;
    int wid  = tid >> 6, lane = tid & 63;
    int col  = lane & 31, hi = lane >> 5;
    int kh   = wid >> 1;               // K-half
    int sub  = wid & 1;                // row-half
    int row_base = blockIdx.x * 64 + sub * 32;

    const float* xrow = X + (size_t)(row_base + col) * D_IN + kh * 32 + hi * 8;

    // staging: waves 0,1 stage hi (kh0,kh1 subtiles); waves 2,3 stage lo. 4 KiB each.
    const _Float16* gsrc = ((wid & 2) ? wlo : whi) + (wid & 1) * 2048 + (size_t)lane * 8;
    const int ldst = ((wid & 2) ? 4096 : 0) + (wid & 1) * 2048;   // shorts, wave-uniform

#define STAGEW(cc, buf) do {                                                  \
        const _Float16* gs_ = gsrc + (size_t)(cc) * 4096;                     \
        _Float16* ld_ = &lw[buf][ldst];                                       \
        _Pragma("unroll")                                                     \
        for (int r = 0; r < 4; ++r)                                           \
            gload_lds16(gs_ + r * 512, ld_ + r * 512);                        \
    } while (0)

    f32x16 aH0[2], aH1[2], aM[2], aLL[2];
#pragma unroll
    for (int nt = 0; nt < 2; ++nt) {
        aH0[nt] = (f32x16)(0.f); aH1[nt] = (f32x16)(0.f);
        aM[nt]  = (f32x16)(0.f); aLL[nt] = (f32x16)(0.f);
    }
    float sum = 0.f, sumsq = 0.f;

    STAGEW(0, 0);
    __syncthreads();   // chunk 0 staged

    for (int c = 0; c < 16; ++c) {
        if (c < 15) STAGEW(c + 1, (c + 1) & 1);
        const float* xp = xrow + c * 64;
        const _Float16* bhp = &lw[c & 1][kh * 2048] + lane * 8;
#pragma unroll
        for (int t = 0; t < 2; ++t) {
            f32x4 x0 = *(const f32x4*)(xp + t * 16);
            f32x4 x1 = *(const f32x4*)(xp + t * 16 + 4);
            float xs[8] = {x0[0], x0[1], x0[2], x0[3], x1[0], x1[1], x1[2], x1[3]};
            f16x8 ahi, alo;
#pragma unroll
            for (int j = 0; j < 8; ++j) {
                float xv = xs[j];
                sum += xv;
                sumsq = fmaf(xv, xv, sumsq);
                _Float16 h = (_Float16)xv;
                ahi[j] = h;
                alo[j] = (_Float16)((xv - (float)h) * 2048.0f);
            }
            const _Float16* base = bhp + t * 1024;
#pragma unroll
            for (int nt = 0; nt < 2; ++nt) {
                f16x8 bh = *(const f16x8*)(base + nt * 512);
                f16x8 bl = *(const f16x8*)(base + nt * 512 + 4096);
                if (t & 1) aH1[nt] = mfma32(ahi, bh, aH1[nt]);
                else       aH0[nt] = mfma32(ahi, bh, aH0[nt]);
                aM[nt]  = mfma32(ahi, bl, aM[nt]);
                aM[nt]  = mfma32(alo, bh, aM[nt]);
                aLL[nt] = mfma32(alo, bl, aLL[nt]);
            }
        }
        __syncthreads();   // next chunk staged; current buffer free
    }

    // precombine per-wave partials: cH = H0+H1 (pairwise), cM = M + LL/2048
    f32x16 cH[2], cM[2];
#pragma unroll
    for (int nt = 0; nt < 2; ++nt) {
        cH[nt] = aH0[nt] + aH1[nt];
        cM[nt] = aM[nt] + aLL[nt] * (1.0f / 2048.0f);
    }

    // K-half 1 waves donate partials via LDS (transposed b32 layout: conflict-free)
    if (kh == 1) {
        float* fb = (float*)&lw[sub][0];
#pragma unroll
        for (int nt = 0; nt < 2; ++nt)
#pragma unroll
            for (int reg = 0; reg < 16; ++reg) {
                fb[((nt * 2 + 0) * 16 + reg) * 64 + lane] = cH[nt][reg];
                fb[((nt * 2 + 1) * 16 + reg) * 64 + lane] = cM[nt][reg];
            }
        s_ss[sub][lane]      = sum;
        s_ss[sub][64 + lane] = sumsq;
    }
    __syncthreads();

    if (kh == 0) {
        const float* fb = (const float*)&lw[sub][0];
#pragma unroll
        for (int nt = 0; nt < 2; ++nt)
#pragma unroll
            for (int reg = 0; reg < 16; ++reg) {
                cH[nt][reg] += fb[((nt * 2 + 0) * 16 + reg) * 64 + lane];
                cM[nt][reg] += fb[((nt * 2 + 1) * 16 + reg) * 64 + lane];
            }
        sum   += s_ss[sub][lane];
        sumsq += s_ss[sub][64 + lane];

        // LN1 stats: combine the two hi-halves of each row
        sum   += __shfl_xor(sum, 32);
        sumsq += __shfl_xor(sumsq, 32);
        float mu   = sum * (1.f / 1024.f);
        float var  = sumsq * (1.f / 1024.f) - mu * mu;
        float rstd = rsqrtf(var + LN_EPS);

        float uv[2], vv[2], g2v[2], b2v[2];
#pragma unroll
        for (int nt = 0; nt < 2; ++nt) {
            int bitc = nt * 32 + col;
            uv[nt] = u[bitc]; vv[nt] = v[bitc]; g2v[nt] = g2[bitc]; b2v[nt] = b2[bitc];
        }

        float ps0 = 0.f, ps1 = 0.f;
#pragma unroll
        for (int reg = 0; reg < 16; ++reg) {
            int r = (reg & 3) + 8 * (reg >> 2) + 4 * hi;   // row within wave, 0..31
            float mu_r = __shfl(mu, r);
            float rs_r = __shfl(rstd, r);
            float d0 = cH[0][reg] + cM[0][reg] * (1.0f / 2048.0f);
            float d1 = cH[1][reg] + cM[1][reg] * (1.0f / 2048.0f);
            float lg0 = rs_r * d0 - rs_r * mu_r * uv[0] + vv[0];
            float lg1 = rs_r * d1 - rs_r * mu_r * uv[1] + vv[1];
            // LN2 over the 64 bits of row r
            float s1 = lg0 + lg1;
            float s2 = lg0 * lg0 + lg1 * lg1;
#pragma unroll
            for (int m = 1; m <= 16; m <<= 1) {
                s1 += __shfl_xor(s1, m);
                s2 += __shfl_xor(s2, m);
            }
            float mean = s1 * (1.f / 64.f);
            float va   = s2 * (1.f / 64.f) - mean * mean;
            float rs2  = rsqrtf(va + LN_EPS);
            float o0 = (lg0 - mean) * rs2 * g2v[0] + b2v[0];
            float o1 = (lg1 - mean) * rs2 * g2v[1] + b2v[1];
            size_t row = (size_t)(row_base + r);
            L[row * 64 + col]      = o0;
            L[row * 64 + 32 + col] = o1;
            ps0 += o0;
            ps1 += o1;
        }

        // per-wave column partial sums over 32 rows; P layout [64][2048]
        ps0 += __shfl_xor(ps0, 32);
        ps1 += __shfl_xor(ps1, 32);
        if (hi == 0) {
            P[(size_t)col * 2048        + blockIdx.x * 2 + sub] = ps0;
            P[(size_t)(32 + col) * 2048 + blockIdx.x * 2 + sub] = ps1;
        }
    }
#undef STAGEW
}

// ---------------- kernel 2: reduce column partials -> column means ----------------
__global__ void reduce_kernel(const float* __restrict__ P, float* __restrict__ cm) {
    int bit = blockIdx.x, t = threadIdx.x;
    float s = 0.f;
    for (int p = t; p < 2048; p += 256) s += P[(size_t)bit * 2048 + p];
    __shared__ float sh[256];
    sh[t] = s;
    __syncthreads();
    for (int off = 128; off > 0; off >>= 1) {
        if (t < off) sh[t] += sh[t + off];
        __syncthreads();
    }
    if (t == 0) cm[bit] = sh[0] * (1.f / (float)N_ROWS);
}

// ---------------- kernel 3: mean-center + fast sign-exact tanh + binarize ----------------
__global__ void final_kernel(const float* __restrict__ L, const float* __restrict__ cm,
                             float* __restrict__ out) {
    __shared__ float cms[64];
    if (threadIdx.x < 64) cms[threadIdx.x] = cm[threadIdx.x];
    __syncthreads();
    const f32x4* L4 = (const f32x4*)L;
    f32x4* H4 = (f32x4*)out;
    f32x4* B4 = (f32x4*)(out + (size_t)N_ROWS * NBIT);
    int total = N_ROWS * NBIT / 4;
    for (int i = blockIdx.x * blockDim.x + threadIdx.x; i < total;
         i += gridDim.x * blockDim.x) {
        f32x4 x = L4[i];
        int bb = (i & 15) * 4;
        f32x4 h, bo;
#pragma unroll
        for (int j = 0; j < 4; ++j) {
            float y  = 0.5f * (x[j] - cms[bb + j]);
            float y2 = y * y;
            float poly = y * fmaf(y2, fmaf(y2, 2.f / 15.f, -1.f / 3.f), 1.f);
            float e  = __expf(2.f * y);
            float ef = 1.f - 2.f / (e + 1.f);
            float hv = (fabsf(y) < 0.5f) ? poly : ef;
            h[j]  = hv;
            bo[j] = hv >= 0.f ? 1.f : -1.f;
        }
        __builtin_nontemporal_store(h, &H4[i]);
        __builtin_nontemporal_store(bo, &B4[i]);
    }
}

extern "C" void kernel_launch(void* const* d_in, const int* in_sizes, int n_in,
                              void* d_out, int out_size, void* d_ws, size_t ws_size,
                              hipStream_t stream) {
    (void)in_sizes; (void)n_in; (void)out_size; (void)ws_size;
    const float* X  = (const float*)d_in[0];
    const float* W  = (const float*)d_in[1];
    const float* bb = (const float*)d_in[2];
    const float* g1 = (const float*)d_in[3];
    const float* b1 = (const float*)d_in[4];
    const float* g2 = (const float*)d_in[5];
    const float* b2 = (const float*)d_in[6];

    char* ws = (char*)d_ws;
    _Float16* whi = (_Float16*)ws;                 // 128 KiB
    _Float16* wlo = (_Float16*)(ws + 131072);      // 128 KiB
    float* u  = (float*)(ws + 262144);             // 256 B
    float* v  = (float*)(ws + 266240);             // 256 B
    float* P  = (float*)(ws + 270336);             // 512 KiB (64*2048*4)
    float* cm = (float*)(ws + 270336 + 64 * 2048 * 4);

    float* out = (float*)d_out;
    float* L   = out + (size_t)N_ROWS * NBIT;      // reuse B-half of d_out as logit scratch

    prep_kernel<<<64, 256, 0, stream>>>(W, bb, g1, b1, whi, wlo, u, v);
    main_kernel<<<1024, 256, 0, stream>>>(X, whi, wlo, u, v, g2, b2, L, P);
    reduce_kernel<<<64, 256, 0, stream>>>(P, cm);
    final_kernel<<<2048, 256, 0, stream>>>(L, cm, out);
}

// Round 10
// 90.237 us; speedup vs baseline: 4.8958x; 4.8958x over previous
//
#include <hip/hip_runtime.h>
#include <stdint.h>

#define N_ROWS 65536
#define D_IN   1024
#define NBIT   64
#define LN_EPS 1e-5f

typedef __attribute__((ext_vector_type(8)))  _Float16 f16x8;
typedef __attribute__((ext_vector_type(4)))  float f32x4;
typedef __attribute__((ext_vector_type(16))) float f32x16;

__device__ __forceinline__ void gload_lds16(const void* g, void* l) {
    __builtin_amdgcn_global_load_lds(
        (const __attribute__((address_space(1))) uint32_t*)g,
        (__attribute__((address_space(3))) uint32_t*)l, 16, 0, 0);
}

__device__ __forceinline__ f32x16 mfma32(f16x8 a, f16x8 b, f32x16 c) {
    return __builtin_amdgcn_mfma_f32_32x32x16_f16(a, b, c, 0, 0, 0);
}

// ---------------- kernel 0: prep split-W fragments + per-bit constants ----------------
// BK=256 chunk-major 32x32x16 fragment layout (4 chunks, 16 t-steps/chunk):
//   bit = nt*32 + (lane&31),  k = c*256 + t*16 + (lane>>5)*8 + j
//   idx = c*16384 + t*1024 + nt*512 + lane*8 + j   (shorts, per hi/lo array)
// whi = fp16(gw); wlo = fp16((gw - whi)*2048)  [exact split, lo scaled to stay normal]
__global__ void prep_kernel(const float* __restrict__ W, const float* __restrict__ bias,
                            const float* __restrict__ g1, const float* __restrict__ b1,
                            _Float16* __restrict__ whi, _Float16* __restrict__ wlo,
                            float* __restrict__ u, float* __restrict__ v) {
    int bit = blockIdx.x;            // 0..63
    int t   = threadIdx.x;           // 0..255
    int nt  = bit >> 5, col = bit & 31;
    float su = 0.f, sv = 0.f;
    for (int d = t; d < D_IN; d += 256) {
        float w  = W[bit * D_IN + d];
        float gw = w * g1[d];
        su += gw;
        sv += w * b1[d];
        int c = d >> 8, tt = (d >> 4) & 15, hi8 = (d >> 3) & 1, j = d & 7;
        int lane = col + 32 * hi8;
        size_t idx = (size_t)c * 16384 + tt * 1024 + nt * 512 + lane * 8 + j;
        _Float16 h = (_Float16)gw;
        whi[idx] = h;
        wlo[idx] = (_Float16)((gw - (float)h) * 2048.0f);
    }
    __shared__ float s1[256], s2[256];
    s1[t] = su; s2[t] = sv;
    __syncthreads();
    for (int off = 128; off > 0; off >>= 1) {
        if (t < off) { s1[t] += s1[t + off]; s2[t] += s2[t + off]; }
        __syncthreads();
    }
    if (t == 0) { u[bit] = s1[0]; v[bit] = s2[0] + bias[bit]; }
}

// ---------------- kernel 1: fused LN1 + split-fp16 32x32 GEMM + LN2 + partials ----------------
// Round-8 structure (validated, 84.4us) with BK=256: X read in 1-KiB contiguous runs
// per row-visit (2x DRAM page locality vs 512-B). W chunk 64 KiB SINGLE-buffered
// (rounds 4/5 proved pipelining is not the limiter; stage is L2-fed and cheap).
// aLL dropped: lo*lo term ~5e-8 RMS, two orders below passing error class.
// 4 waves x 32 rows = 128 rows/block, grid 512 (2 blocks/CU).
__global__ void __launch_bounds__(256, 2) main_kernel(
        const float* __restrict__ X,
        const _Float16* __restrict__ whi, const _Float16* __restrict__ wlo,
        const float* __restrict__ u, const float* __restrict__ v,
        const float* __restrict__ g2, const float* __restrict__ b2,
        float* __restrict__ L, float* __restrict__ P) {
    __shared__ _Float16 lw[32768];   // hi [0,16384) | lo [16384,32768) shorts, 64 KiB
    int tid  = threadIdx.x;
    int wid  = tid >> 6, lane = tid & 63;
    int col  = lane & 31, hi = lane >> 5;
    int row_base = blockIdx.x * 128 + wid * 32;

    const float* xrow = X + (size_t)(row_base + col) * D_IN + hi * 8;

    // staging: waves 0,1 -> whi halves; waves 2,3 -> wlo halves (16 KiB each, linear)
    const _Float16* gsrc = ((wid & 2) ? wlo : whi) + (wid & 1) * 8192 + (size_t)lane * 8;
    const int ldst = ((wid & 2) ? 16384 : 0) + (wid & 1) * 8192;   // shorts, wave-uniform

#define STAGEW(cc) do {                                                       \
        const _Float16* gs_ = gsrc + (size_t)(cc) * 16384;                    \
        _Float16* ld_ = &lw[ldst];                                            \
        _Pragma("unroll")                                                     \
        for (int r = 0; r < 16; ++r)                                          \
            gload_lds16(gs_ + r * 512, ld_ + r * 512);                        \
    } while (0)

    f32x16 aH0[2], aH1[2], aM[2];
#pragma unroll
    for (int nt = 0; nt < 2; ++nt) {
        aH0[nt] = (f32x16)(0.f); aH1[nt] = (f32x16)(0.f); aM[nt] = (f32x16)(0.f);
    }
    float sum = 0.f, sumsq = 0.f;

    STAGEW(0);
    __syncthreads();   // chunk 0 staged

    for (int c = 0; c < 4; ++c) {
        const float* xp = xrow + c * 256;
        const _Float16* lwb = &lw[0] + lane * 8;
#pragma unroll
        for (int t = 0; t < 16; ++t) {
            f32x4 x0 = *(const f32x4*)(xp + t * 16);
            f32x4 x1 = *(const f32x4*)(xp + t * 16 + 4);
            float xs[8] = {x0[0], x0[1], x0[2], x0[3], x1[0], x1[1], x1[2], x1[3]};
            f16x8 ahi, alo;
#pragma unroll
            for (int j = 0; j < 8; ++j) {
                float xv = xs[j];
                sum += xv;
                sumsq = fmaf(xv, xv, sumsq);
                _Float16 h = (_Float16)xv;
                ahi[j] = h;
                alo[j] = (_Float16)((xv - (float)h) * 2048.0f);
            }
            const _Float16* base = lwb + t * 1024;
#pragma unroll
            for (int nt = 0; nt < 2; ++nt) {
                f16x8 bh = *(const f16x8*)(base + nt * 512);
                f16x8 bl = *(const f16x8*)(base + nt * 512 + 16384);
                if (t & 1) aH1[nt] = mfma32(ahi, bh, aH1[nt]);
                else       aH0[nt] = mfma32(ahi, bh, aH0[nt]);
                aM[nt] = mfma32(ahi, bl, aM[nt]);
                aM[nt] = mfma32(alo, bh, aM[nt]);
            }
        }
        __syncthreads();               // all waves done reading this chunk
        if (c < 3) {
            STAGEW(c + 1);
            __syncthreads();           // next chunk staged (vmcnt(0) drain)
        }
    }

    // LN1 stats: combine the two hi-halves of each row
    sum   += __shfl_xor(sum, 32);
    sumsq += __shfl_xor(sumsq, 32);
    float mu   = sum * (1.f / 1024.f);
    float var  = sumsq * (1.f / 1024.f) - mu * mu;
    float rstd = rsqrtf(var + LN_EPS);

    float uv[2], vv[2], g2v[2], b2v[2];
#pragma unroll
    for (int nt = 0; nt < 2; ++nt) {
        int bitc = nt * 32 + col;
        uv[nt] = u[bitc]; vv[nt] = v[bitc]; g2v[nt] = g2[bitc]; b2v[nt] = b2[bitc];
    }

    float ps0 = 0.f, ps1 = 0.f;
#pragma unroll
    for (int reg = 0; reg < 16; ++reg) {
        int r = (reg & 3) + 8 * (reg >> 2) + 4 * hi;   // row within wave, 0..31
        float mu_r = __shfl(mu, r);
        float rs_r = __shfl(rstd, r);
        float d0 = (aH0[0][reg] + aH1[0][reg]) + aM[0][reg] * (1.0f / 2048.0f);
        float d1 = (aH0[1][reg] + aH1[1][reg]) + aM[1][reg] * (1.0f / 2048.0f);
        float lg0 = rs_r * d0 - rs_r * mu_r * uv[0] + vv[0];
        float lg1 = rs_r * d1 - rs_r * mu_r * uv[1] + vv[1];
        // LN2 over the 64 bits of row r
        float s1 = lg0 + lg1;
        float s2 = lg0 * lg0 + lg1 * lg1;
#pragma unroll
        for (int m = 1; m <= 16; m <<= 1) {
            s1 += __shfl_xor(s1, m);
            s2 += __shfl_xor(s2, m);
        }
        float mean = s1 * (1.f / 64.f);
        float va   = s2 * (1.f / 64.f) - mean * mean;
        float rs2  = rsqrtf(va + LN_EPS);
        float o0 = (lg0 - mean) * rs2 * g2v[0] + b2v[0];
        float o1 = (lg1 - mean) * rs2 * g2v[1] + b2v[1];
        size_t row = (size_t)(row_base + r);
        L[row * 64 + col]      = o0;
        L[row * 64 + 32 + col] = o1;
        ps0 += o0;
        ps1 += o1;
    }

    // per-wave column partial sums over the wave's 32 rows; P layout [64][2048]
    ps0 += __shfl_xor(ps0, 32);
    ps1 += __shfl_xor(ps1, 32);
    if (hi == 0) {
        P[(size_t)col * 2048        + blockIdx.x * 4 + wid] = ps0;
        P[(size_t)(32 + col) * 2048 + blockIdx.x * 4 + wid] = ps1;
    }
#undef STAGEW
}

// ---------------- kernel 2: reduce column partials -> column means ----------------
__global__ void reduce_kernel(const float* __restrict__ P, float* __restrict__ cm) {
    int bit = blockIdx.x, t = threadIdx.x;
    float s = 0.f;
    for (int p = t; p < 2048; p += 256) s += P[(size_t)bit * 2048 + p];
    __shared__ float sh[256];
    sh[t] = s;
    __syncthreads();
    for (int off = 128; off > 0; off >>= 1) {
        if (t < off) sh[t] += sh[t + off];
        __syncthreads();
    }
    if (t == 0) cm[bit] = sh[0] * (1.f / (float)N_ROWS);
}

// ---------------- kernel 3: mean-center + fast sign-exact tanh + binarize ----------------
__global__ void final_kernel(const float* __restrict__ L, const float* __restrict__ cm,
                             float* __restrict__ out) {
    __shared__ float cms[64];
    if (threadIdx.x < 64) cms[threadIdx.x] = cm[threadIdx.x];
    __syncthreads();
    const f32x4* L4 = (const f32x4*)L;
    f32x4* H4 = (f32x4*)out;
    f32x4* B4 = (f32x4*)(out + (size_t)N_ROWS * NBIT);
    int total = N_ROWS * NBIT / 4;
    for (int i = blockIdx.x * blockDim.x + threadIdx.x; i < total;
         i += gridDim.x * blockDim.x) {
        f32x4 x = L4[i];
        int bb = (i & 15) * 4;
        f32x4 h, bo;
#pragma unroll
        for (int j = 0; j < 4; ++j) {
            float y  = 0.5f * (x[j] - cms[bb + j]);
            float y2 = y * y;
            float poly = y * fmaf(y2, fmaf(y2, 2.f / 15.f, -1.f / 3.f), 1.f);
            float e  = __expf(2.f * y);
            float ef = 1.f - 2.f / (e + 1.f);
            float hv = (fabsf(y) < 0.5f) ? poly : ef;
            h[j]  = hv;
            bo[j] = hv >= 0.f ? 1.f : -1.f;
        }
        __builtin_nontemporal_store(h, &H4[i]);
        __builtin_nontemporal_store(bo, &B4[i]);
    }
}

extern "C" void kernel_launch(void* const* d_in, const int* in_sizes, int n_in,
                              void* d_out, int out_size, void* d_ws, size_t ws_size,
                              hipStream_t stream) {
    (void)in_sizes; (void)n_in; (void)out_size; (void)ws_size;
    const float* X  = (const float*)d_in[0];
    const float* W  = (const float*)d_in[1];
    const float* bb = (const float*)d_in[2];
    const float* g1 = (const float*)d_in[3];
    const float* b1 = (const float*)d_in[4];
    const float* g2 = (const float*)d_in[5];
    const float* b2 = (const float*)d_in[6];

    char* ws = (char*)d_ws;
    _Float16* whi = (_Float16*)ws;                 // 128 KiB
    _Float16* wlo = (_Float16*)(ws + 131072);      // 128 KiB
    float* u  = (float*)(ws + 262144);             // 256 B
    float* v  = (float*)(ws + 266240);             // 256 B
    float* P  = (float*)(ws + 270336);             // 512 KiB (64*2048*4)
    float* cm = (float*)(ws + 270336 + 64 * 2048 * 4);

    float* out = (float*)d_out;
    float* L   = out + (size_t)N_ROWS * NBIT;      // reuse B-half of d_out as logit scratch

    prep_kernel<<<64, 256, 0, stream>>>(W, bb, g1, b1, whi, wlo, u, v);
    main_kernel<<<512, 256, 0, stream>>>(X, whi, wlo, u, v, g2, b2, L, P);
    reduce_kernel<<<64, 256, 0, stream>>>(P, cm);
    final_kernel<<<2048, 256, 0, stream>>>(L, cm, out);
}

// Round 12
// 81.302 us; speedup vs baseline: 5.4338x; 1.1099x over previous
//
#include <hip/hip_runtime.h>
#include <stdint.h>

#define N_ROWS 65536
#define D_IN   1024
#define NBIT   64
#define LN_EPS 1e-5f

typedef __attribute__((ext_vector_type(8)))  _Float16 f16x8;
typedef __attribute__((ext_vector_type(4)))  _Float16 f16x4;
typedef __attribute__((ext_vector_type(2)))  _Float16 f16x2;
typedef __attribute__((ext_vector_type(4)))  float f32x4;
typedef __attribute__((ext_vector_type(16))) float f32x16;

__device__ __forceinline__ void gload_lds16(const void* g, void* l) {
    __builtin_amdgcn_global_load_lds(
        (const __attribute__((address_space(1))) uint32_t*)g,
        (__attribute__((address_space(3))) uint32_t*)l, 16, 0, 0);
}

__device__ __forceinline__ f32x16 mfma32(f16x8 a, f16x8 b, f32x16 c) {
    return __builtin_amdgcn_mfma_f32_32x32x16_f16(a, b, c, 0, 0, 0);
}

__device__ __forceinline__ f16x2 pkrtz(float a, float b) {
    return __builtin_bit_cast(f16x2, __builtin_amdgcn_cvt_pkrtz(a, b));
}

// exact two-way split of 8 fp32 into fp16 hi + scaled fp16 lo, via packed RTZ converts
__device__ __forceinline__ void split8(f32x4 x0, f32x4 x1,
                                       f16x8& ahi, f16x8& alo,
                                       float& sum, float& sumsq) {
    float xs[8] = {x0[0], x0[1], x0[2], x0[3], x1[0], x1[1], x1[2], x1[3]};
#pragma unroll
    for (int j = 0; j < 8; ++j) {
        sum += xs[j];
        sumsq = fmaf(xs[j], xs[j], sumsq);
    }
    f16x2 h01 = pkrtz(xs[0], xs[1]);
    f16x2 h23 = pkrtz(xs[2], xs[3]);
    f16x2 h45 = pkrtz(xs[4], xs[5]);
    f16x2 h67 = pkrtz(xs[6], xs[7]);
    f16x2 l01 = pkrtz((xs[0] - (float)h01[0]) * 2048.f,
                      (xs[1] - (float)h01[1]) * 2048.f);
    f16x2 l23 = pkrtz((xs[2] - (float)h23[0]) * 2048.f,
                      (xs[3] - (float)h23[1]) * 2048.f);
    f16x2 l45 = pkrtz((xs[4] - (float)h45[0]) * 2048.f,
                      (xs[5] - (float)h45[1]) * 2048.f);
    f16x2 l67 = pkrtz((xs[6] - (float)h67[0]) * 2048.f,
                      (xs[7] - (float)h67[1]) * 2048.f);
    f16x4 a0 = __builtin_shufflevector(h01, h23, 0, 1, 2, 3);
    f16x4 a1 = __builtin_shufflevector(h45, h67, 0, 1, 2, 3);
    ahi = __builtin_shufflevector(a0, a1, 0, 1, 2, 3, 4, 5, 6, 7);
    f16x4 b0 = __builtin_shufflevector(l01, l23, 0, 1, 2, 3);
    f16x4 b1 = __builtin_shufflevector(l45, l67, 0, 1, 2, 3);
    alo = __builtin_shufflevector(b0, b1, 0, 1, 2, 3, 4, 5, 6, 7);
}

// ---------------- kernel 0: prep split-W fragments + per-bit constants ----------------
// BK=128 chunk-major 32x32x16 fragment layout (8 chunks, 8 t-steps/chunk):
//   bit = nt*32 + (lane&31),  k = c*128 + t*16 + (lane>>5)*8 + j
//   idx = c*8192 + t*1024 + nt*512 + lane*8 + j   (shorts, per hi/lo array)
__global__ void prep_kernel(const float* __restrict__ W, const float* __restrict__ bias,
                            const float* __restrict__ g1, const float* __restrict__ b1,
                            _Float16* __restrict__ whi, _Float16* __restrict__ wlo,
                            float* __restrict__ u, float* __restrict__ v) {
    int bit = blockIdx.x;            // 0..63
    int t   = threadIdx.x;           // 0..255
    int nt  = bit >> 5, col = bit & 31;
    float su = 0.f, sv = 0.f;
    for (int d = t; d < D_IN; d += 256) {
        float w  = W[bit * D_IN + d];
        float gw = w * g1[d];
        su += gw;
        sv += w * b1[d];
        int tg = d >> 4, c = tg >> 3, tt = tg & 7;
        int hi8 = (d >> 3) & 1, j = d & 7;
        int lane = col + 32 * hi8;
        size_t idx = (size_t)c * 8192 + tt * 1024 + nt * 512 + lane * 8 + j;
        _Float16 h = (_Float16)gw;
        whi[idx] = h;
        wlo[idx] = (_Float16)((gw - (float)h) * 2048.0f);
    }
    __shared__ float s1[256], s2[256];
    s1[t] = su; s2[t] = sv;
    __syncthreads();
    for (int off = 128; off > 0; off >>= 1) {
        if (t < off) { s1[t] += s1[t + off]; s2[t] += s2[t + off]; }
        __syncthreads();
    }
    if (t == 0) { u[bit] = s1[0]; v[bit] = s2[0] + bias[bit]; }
}

// ---------------- kernel 1: fused LN1 + split-fp16 32x32 GEMM + LN2 + partials ----------------
// Round-8 validated structure (BK=128, W dbuf 64 KiB, 4 waves x 32 rows, grid 512,
// 2 blocks/CU) + distance-1 X prefetch across counted-vmcnt barriers.
__global__ void __launch_bounds__(256, 2) main_kernel(
        const float* __restrict__ X,
        const _Float16* __restrict__ whi, const _Float16* __restrict__ wlo,
        const float* __restrict__ u, const float* __restrict__ v,
        const float* __restrict__ g2, const float* __restrict__ b2,
        float* __restrict__ L, float* __restrict__ P) {
    __shared__ _Float16 lw[2][16384];   // [buf][hi:0..8192 | lo:8192..16384] shorts
    int tid  = threadIdx.x;
    int wid  = tid >> 6, lane = tid & 63;
    int col  = lane & 31, hi = lane >> 5;
    int row_base = blockIdx.x * 128 + wid * 32;

    const float* xrow = X + (size_t)(row_base + col) * D_IN + hi * 8;

    // staging: waves 0,1 -> whi halves; waves 2,3 -> wlo halves (8 KiB each, linear)
    const _Float16* gsrc = ((wid & 2) ? wlo : whi) + (wid & 1) * 4096 + (size_t)lane * 8;
    const int ldst = ((wid & 2) ? 8192 : 0) + (wid & 1) * 4096;   // shorts, wave-uniform

#define STAGEW(cc, buf) do {                                                  \
        const _Float16* gs_ = gsrc + (size_t)(cc) * 8192;                     \
        _Float16* ld_ = &lw[buf][ldst];                                       \
        _Pragma("unroll")                                                     \
        for (int r = 0; r < 8; ++r)                                           \
            gload_lds16(gs_ + r * 512, ld_ + r * 512);                        \
    } while (0)

#define SB0 __builtin_amdgcn_sched_barrier(0)

    f32x16 aH0[2], aH1[2], aM[2];
#pragma unroll
    for (int nt = 0; nt < 2; ++nt) {
        aH0[nt] = (f32x16)(0.f); aH1[nt] = (f32x16)(0.f); aM[nt] = (f32x16)(0.f);
    }
    float sum = 0.f, sumsq = 0.f;
    f32x4 p0, p1, p2, p3;   // prefetch regs: next chunk's t=0,1

    // prologue: stage chunk 0, prefetch chunk-0 t=0,1; full drain once
    STAGEW(0, 0);
    p0 = *(const f32x4*)(xrow);
    p1 = *(const f32x4*)(xrow + 4);
    p2 = *(const f32x4*)(xrow + 16);
    p3 = *(const f32x4*)(xrow + 20);
    __syncthreads();

#pragma unroll
    for (int c = 0; c < 8; ++c) {
        if (c < 7) STAGEW(c + 1, (c + 1) & 1);
        const float* xp  = xrow + c * 128;
        const _Float16* lwb = &lw[c & 1][0] + lane * 8;
        f16x8 ahi, alo;
        // t = 0,1 from prefetch regs
#pragma unroll
        for (int t = 0; t < 2; ++t) {
            split8(t ? p2 : p0, t ? p3 : p1, ahi, alo, sum, sumsq);
            const _Float16* base = lwb + t * 1024;
#pragma unroll
            for (int nt = 0; nt < 2; ++nt) {
                f16x8 bh = *(const f16x8*)(base + nt * 512);
                f16x8 bl = *(const f16x8*)(base + nt * 512 + 8192);
                if (t & 1) aH1[nt] = mfma32(ahi, bh, aH1[nt]);
                else       aH0[nt] = mfma32(ahi, bh, aH0[nt]);
                aM[nt] = mfma32(ahi, bl, aM[nt]);
                aM[nt] = mfma32(alo, bh, aM[nt]);
            }
        }
        // t = 2..7 loaded in-chunk
#pragma unroll
        for (int t = 2; t < 8; ++t) {
            f32x4 x0 = *(const f32x4*)(xp + t * 16);
            f32x4 x1 = *(const f32x4*)(xp + t * 16 + 4);
            split8(x0, x1, ahi, alo, sum, sumsq);
            const _Float16* base = lwb + t * 1024;
#pragma unroll
            for (int nt = 0; nt < 2; ++nt) {
                f16x8 bh = *(const f16x8*)(base + nt * 512);
                f16x8 bl = *(const f16x8*)(base + nt * 512 + 8192);
                if (t & 1) aH1[nt] = mfma32(ahi, bh, aH1[nt]);
                else       aH0[nt] = mfma32(ahi, bh, aH0[nt]);
                aM[nt] = mfma32(ahi, bl, aM[nt]);
                aM[nt] = mfma32(alo, bh, aM[nt]);
            }
        }
        if (c < 7) {
            // prefetch next chunk's t=0,1 (issued last -> the 4 left in flight)
            const float* xn = xrow + (c + 1) * 128;
            p0 = *(const f32x4*)(xn);
            p1 = *(const f32x4*)(xn + 4);
            p2 = *(const f32x4*)(xn + 16);
            p3 = *(const f32x4*)(xn + 20);
            SB0;
            // W(c+1) and all in-chunk X retired (in-order); only the 4 PF loads remain
            asm volatile("s_waitcnt vmcnt(4)" ::: "memory");
            __builtin_amdgcn_s_barrier();
        }
    }

    // ---- epilogue (validated round-8 math; aLL term dropped: empirically identical) ----
    sum   += __shfl_xor(sum, 32);
    sumsq += __shfl_xor(sumsq, 32);
    float mu   = sum * (1.f / 1024.f);
    float var  = sumsq * (1.f / 1024.f) - mu * mu;
    float rstd = rsqrtf(var + LN_EPS);

    float uv[2], vv[2], g2v[2], b2v[2];
#pragma unroll
    for (int nt = 0; nt < 2; ++nt) {
        int bitc = nt * 32 + col;
        uv[nt] = u[bitc]; vv[nt] = v[bitc]; g2v[nt] = g2[bitc]; b2v[nt] = b2[bitc];
    }

    float ps0 = 0.f, ps1 = 0.f;
#pragma unroll
    for (int reg = 0; reg < 16; ++reg) {
        int r = (reg & 3) + 8 * (reg >> 2) + 4 * hi;   // row within wave, 0..31
        float mu_r = __shfl(mu, r);
        float rs_r = __shfl(rstd, r);
        float d0 = (aH0[0][reg] + aH1[0][reg]) + aM[0][reg] * (1.0f / 2048.0f);
        float d1 = (aH0[1][reg] + aH1[1][reg]) + aM[1][reg] * (1.0f / 2048.0f);
        float lg0 = rs_r * d0 - rs_r * mu_r * uv[0] + vv[0];
        float lg1 = rs_r * d1 - rs_r * mu_r * uv[1] + vv[1];
        float s1 = lg0 + lg1;
        float s2 = lg0 * lg0 + lg1 * lg1;
#pragma unroll
        for (int m = 1; m <= 16; m <<= 1) {
            s1 += __shfl_xor(s1, m);
            s2 += __shfl_xor(s2, m);
        }
        float mean = s1 * (1.f / 64.f);
        float va   = s2 * (1.f / 64.f) - mean * mean;
        float rs2  = rsqrtf(va + LN_EPS);
        float o0 = (lg0 - mean) * rs2 * g2v[0] + b2v[0];
        float o1 = (lg1 - mean) * rs2 * g2v[1] + b2v[1];
        size_t row = (size_t)(row_base + r);
        L[row * 64 + col]      = o0;
        L[row * 64 + 32 + col] = o1;
        ps0 += o0;
        ps1 += o1;
    }

    ps0 += __shfl_xor(ps0, 32);
    ps1 += __shfl_xor(ps1, 32);
    if (hi == 0) {
        P[(size_t)col * 2048        + blockIdx.x * 4 + wid] = ps0;
        P[(size_t)(32 + col) * 2048 + blockIdx.x * 4 + wid] = ps1;
    }
#undef STAGEW
#undef SB0
}

// ---------------- kernel 2: reduce column partials -> column means ----------------
__global__ void reduce_kernel(const float* __restrict__ P, float* __restrict__ cm) {
    int bit = blockIdx.x, t = threadIdx.x;
    float s = 0.f;
    for (int p = t; p < 2048; p += 256) s += P[(size_t)bit * 2048 + p];
    __shared__ float sh[256];
    sh[t] = s;
    __syncthreads();
    for (int off = 128; off > 0; off >>= 1) {
        if (t < off) sh[t] += sh[t + off];
        __syncthreads();
    }
    if (t == 0) cm[bit] = sh[0] * (1.f / (float)N_ROWS);
}

// ---------------- kernel 3: mean-center + fast sign-exact tanh + binarize ----------------
__global__ void final_kernel(const float* __restrict__ L, const float* __restrict__ cm,
                             float* __restrict__ out) {
    __shared__ float cms[64];
    if (threadIdx.x < 64) cms[threadIdx.x] = cm[threadIdx.x];
    __syncthreads();
    const f32x4* L4 = (const f32x4*)L;
    f32x4* H4 = (f32x4*)out;
    f32x4* B4 = (f32x4*)(out + (size_t)N_ROWS * NBIT);
    int total = N_ROWS * NBIT / 4;
    for (int i = blockIdx.x * blockDim.x + threadIdx.x; i < total;
         i += gridDim.x * blockDim.x) {
        f32x4 x = L4[i];
        int bb = (i & 15) * 4;
        f32x4 h, bo;
#pragma unroll
        for (int j = 0; j < 4; ++j) {
            float y  = 0.5f * (x[j] - cms[bb + j]);
            float y2 = y * y;
            float poly = y * fmaf(y2, fmaf(y2, 2.f / 15.f, -1.f / 3.f), 1.f);
            float e  = __expf(2.f * y);
            float ef = 1.f - 2.f / (e + 1.f);
            float hv = (fabsf(y) < 0.5f) ? poly : ef;
            h[j]  = hv;
            bo[j] = hv >= 0.f ? 1.f : -1.f;
        }
        __builtin_nontemporal_store(h, &H4[i]);
        __builtin_nontemporal_store(bo, &B4[i]);
    }
}

extern "C" void kernel_launch(void* const* d_in, const int* in_sizes, int n_in,
                              void* d_out, int out_size, void* d_ws, size_t ws_size,
                              hipStream_t stream) {
    (void)in_sizes; (void)n_in; (void)out_size; (void)ws_size;
    const float* X  = (const float*)d_in[0];
    const float* W  = (const float*)d_in[1];
    const float* bb = (const float*)d_in[2];
    const float* g1 = (const float*)d_in[3];
    const float* b1 = (const float*)d_in[4];
    const float* g2 = (const float*)d_in[5];
    const float* b2 = (const float*)d_in[6];

    char* ws = (char*)d_ws;
    _Float16* whi = (_Float16*)ws;                 // 128 KiB
    _Float16* wlo = (_Float16*)(ws + 131072);      // 128 KiB
    float* u  = (float*)(ws + 262144);             // 256 B
    float* v  = (float*)(ws + 266240);             // 256 B
    float* P  = (float*)(ws + 270336);             // 512 KiB (64*2048*4)
    float* cm = (float*)(ws + 270336 + 64 * 2048 * 4);

    float* out = (float*)d_out;
    float* L   = out + (size_t)N_ROWS * NBIT;      // reuse B-half of d_out as logit scratch

    prep_kernel<<<64, 256, 0, stream>>>(W, bb, g1, b1, whi, wlo, u, v);
    main_kernel<<<512, 256, 0, stream>>>(X, whi, wlo, u, v, g2, b2, L, P);
    reduce_kernel<<<64, 256, 0, stream>>>(P, cm);
    final_kernel<<<2048, 256, 0, stream>>>(L, cm, out);
}

// Round 13
// 80.544 us; speedup vs baseline: 5.4849x; 1.0094x over previous
//
#include <hip/hip_runtime.h>
#include <stdint.h>

#define N_ROWS 65536
#define D_IN   1024
#define NBIT   64
#define LN_EPS 1e-5f

typedef __attribute__((ext_vector_type(8)))  _Float16 f16x8;
typedef __attribute__((ext_vector_type(4)))  _Float16 f16x4;
typedef __attribute__((ext_vector_type(2)))  _Float16 f16x2;
typedef __attribute__((ext_vector_type(4)))  float f32x4;
typedef __attribute__((ext_vector_type(16))) float f32x16;

__device__ __forceinline__ void gload_lds16(const void* g, void* l) {
    __builtin_amdgcn_global_load_lds(
        (const __attribute__((address_space(1))) uint32_t*)g,
        (__attribute__((address_space(3))) uint32_t*)l, 16, 0, 0);
}

__device__ __forceinline__ f32x16 mfma32(f16x8 a, f16x8 b, f32x16 c) {
    return __builtin_amdgcn_mfma_f32_32x32x16_f16(a, b, c, 0, 0, 0);
}

__device__ __forceinline__ f16x2 pkrtz(float a, float b) {
    return __builtin_bit_cast(f16x2, __builtin_amdgcn_cvt_pkrtz(a, b));
}

// exact two-way split of 8 fp32 into fp16 hi + scaled fp16 lo, via packed RTZ converts
__device__ __forceinline__ void split8(f32x4 x0, f32x4 x1,
                                       f16x8& ahi, f16x8& alo,
                                       float& sum, float& sumsq) {
    float xs[8] = {x0[0], x0[1], x0[2], x0[3], x1[0], x1[1], x1[2], x1[3]};
#pragma unroll
    for (int j = 0; j < 8; ++j) {
        sum += xs[j];
        sumsq = fmaf(xs[j], xs[j], sumsq);
    }
    f16x2 h01 = pkrtz(xs[0], xs[1]);
    f16x2 h23 = pkrtz(xs[2], xs[3]);
    f16x2 h45 = pkrtz(xs[4], xs[5]);
    f16x2 h67 = pkrtz(xs[6], xs[7]);
    f16x2 l01 = pkrtz((xs[0] - (float)h01[0]) * 2048.f,
                      (xs[1] - (float)h01[1]) * 2048.f);
    f16x2 l23 = pkrtz((xs[2] - (float)h23[0]) * 2048.f,
                      (xs[3] - (float)h23[1]) * 2048.f);
    f16x2 l45 = pkrtz((xs[4] - (float)h45[0]) * 2048.f,
                      (xs[5] - (float)h45[1]) * 2048.f);
    f16x2 l67 = pkrtz((xs[6] - (float)h67[0]) * 2048.f,
                      (xs[7] - (float)h67[1]) * 2048.f);
    f16x4 a0 = __builtin_shufflevector(h01, h23, 0, 1, 2, 3);
    f16x4 a1 = __builtin_shufflevector(h45, h67, 0, 1, 2, 3);
    ahi = __builtin_shufflevector(a0, a1, 0, 1, 2, 3, 4, 5, 6, 7);
    f16x4 b0 = __builtin_shufflevector(l01, l23, 0, 1, 2, 3);
    f16x4 b1 = __builtin_shufflevector(l45, l67, 0, 1, 2, 3);
    alo = __builtin_shufflevector(b0, b1, 0, 1, 2, 3, 4, 5, 6, 7);
}

// ---------------- kernel 0: prep split-W fragments + per-bit constants ----------------
// BK=128 chunk-major 32x32x16 fragment layout (8 chunks, 8 t-steps/chunk):
//   bit = nt*32 + (lane&31),  k = c*128 + t*16 + (lane>>5)*8 + j
//   idx = c*8192 + t*1024 + nt*512 + lane*8 + j   (shorts, per hi/lo array)
__global__ void prep_kernel(const float* __restrict__ W, const float* __restrict__ bias,
                            const float* __restrict__ g1, const float* __restrict__ b1,
                            _Float16* __restrict__ whi, _Float16* __restrict__ wlo,
                            float* __restrict__ u, float* __restrict__ v) {
    int bit = blockIdx.x;            // 0..63
    int t   = threadIdx.x;           // 0..255
    int nt  = bit >> 5, col = bit & 31;
    float su = 0.f, sv = 0.f;
    for (int d = t; d < D_IN; d += 256) {
        float w  = W[bit * D_IN + d];
        float gw = w * g1[d];
        su += gw;
        sv += w * b1[d];
        int tg = d >> 4, c = tg >> 3, tt = tg & 7;
        int hi8 = (d >> 3) & 1, j = d & 7;
        int lane = col + 32 * hi8;
        size_t idx = (size_t)c * 8192 + tt * 1024 + nt * 512 + lane * 8 + j;
        _Float16 h = (_Float16)gw;
        whi[idx] = h;
        wlo[idx] = (_Float16)((gw - (float)h) * 2048.0f);
    }
    __shared__ float s1[256], s2[256];
    s1[t] = su; s2[t] = sv;
    __syncthreads();
    for (int off = 128; off > 0; off >>= 1) {
        if (t < off) { s1[t] += s1[t + off]; s2[t] += s2[t + off]; }
        __syncthreads();
    }
    if (t == 0) { u[bit] = s1[0]; v[bit] = s2[0] + bias[bit]; }
}

// ---------------- kernel 1: fused LN1 + split-fp16 32x32 GEMM + LN2 + partials ----------------
// R12 structure, with next-chunk X prefetch moved to chunk TOP (double-buffered pa/pb
// register sets): prefetch is in flight for the whole chunk (~1100cy >> HBM latency),
// so the end-of-chunk barrier's vmcnt(0) drain is free.
__global__ void __launch_bounds__(256, 2) main_kernel(
        const float* __restrict__ X,
        const _Float16* __restrict__ whi, const _Float16* __restrict__ wlo,
        const float* __restrict__ u, const float* __restrict__ v,
        const float* __restrict__ g2, const float* __restrict__ b2,
        float* __restrict__ L, float* __restrict__ P) {
    __shared__ _Float16 lw[2][16384];   // [buf][hi:0..8192 | lo:8192..16384] shorts
    int tid  = threadIdx.x;
    int wid  = tid >> 6, lane = tid & 63;
    int col  = lane & 31, hi = lane >> 5;
    int row_base = blockIdx.x * 128 + wid * 32;

    const float* xrow = X + (size_t)(row_base + col) * D_IN + hi * 8;

    // staging: waves 0,1 -> whi halves; waves 2,3 -> wlo halves (8 KiB each, linear)
    const _Float16* gsrc = ((wid & 2) ? wlo : whi) + (wid & 1) * 4096 + (size_t)lane * 8;
    const int ldst = ((wid & 2) ? 8192 : 0) + (wid & 1) * 4096;   // shorts, wave-uniform

#define STAGEW(cc, buf) do {                                                  \
        const _Float16* gs_ = gsrc + (size_t)(cc) * 8192;                     \
        _Float16* ld_ = &lw[buf][ldst];                                       \
        _Pragma("unroll")                                                     \
        for (int r = 0; r < 8; ++r)                                           \
            gload_lds16(gs_ + r * 512, ld_ + r * 512);                        \
    } while (0)

#define SB0 __builtin_amdgcn_sched_barrier(0)

    f32x16 aH0[2], aH1[2], aM[2];
#pragma unroll
    for (int nt = 0; nt < 2; ++nt) {
        aH0[nt] = (f32x16)(0.f); aH1[nt] = (f32x16)(0.f); aM[nt] = (f32x16)(0.f);
    }
    float sum = 0.f, sumsq = 0.f;
    f32x4 pa0, pa1, pa2, pa3, pb0, pb1, pb2, pb3;   // dbuf prefetch: t=0,1 of a chunk

    // one t-step's MFMA cluster (constant odd/nt at every call site -> fully inlined)
#define DO_MFMA(odd, AH, AL, BASE) do {                                       \
        _Pragma("unroll")                                                     \
        for (int nt_ = 0; nt_ < 2; ++nt_) {                                   \
            f16x8 bh_ = *(const f16x8*)((BASE) + nt_ * 512);                  \
            f16x8 bl_ = *(const f16x8*)((BASE) + nt_ * 512 + 8192);           \
            if (odd) aH1[nt_] = mfma32(AH, bh_, aH1[nt_]);                    \
            else     aH0[nt_] = mfma32(AH, bh_, aH0[nt_]);                    \
            aM[nt_] = mfma32(AH, bl_, aM[nt_]);                               \
            aM[nt_] = mfma32(AL, bh_, aM[nt_]);                               \
        }                                                                     \
    } while (0)

    // CHUNK(c): consume IN regs (t=0,1), issue OUT prefetch for c+1 at TOP.
#define CHUNK(c, I0, I1, I2, I3, O0, O1, O2, O3) do {                         \
        if ((c) < 7) {                                                        \
            STAGEW((c) + 1, ((c) + 1) & 1);                                   \
            const float* xn_ = xrow + ((c) + 1) * 128;                        \
            O0 = *(const f32x4*)(xn_);                                        \
            O1 = *(const f32x4*)(xn_ + 4);                                    \
            O2 = *(const f32x4*)(xn_ + 16);                                   \
            O3 = *(const f32x4*)(xn_ + 20);                                   \
            SB0;                                                              \
        }                                                                     \
        const float* xp_ = xrow + (c) * 128;                                  \
        const _Float16* lwb_ = &lw[(c) & 1][0] + lane * 8;                    \
        f16x8 ahi_, alo_;                                                     \
        split8(I0, I1, ahi_, alo_, sum, sumsq);                               \
        DO_MFMA(0, ahi_, alo_, lwb_);                                         \
        split8(I2, I3, ahi_, alo_, sum, sumsq);                               \
        DO_MFMA(1, ahi_, alo_, lwb_ + 1024);                                  \
        _Pragma("unroll")                                                     \
        for (int t = 2; t < 8; ++t) {                                         \
            f32x4 x0_ = *(const f32x4*)(xp_ + t * 16);                        \
            f32x4 x1_ = *(const f32x4*)(xp_ + t * 16 + 4);                    \
            split8(x0_, x1_, ahi_, alo_, sum, sumsq);                         \
            const _Float16* base_ = lwb_ + t * 1024;                          \
            if (t & 1) DO_MFMA(1, ahi_, alo_, base_);                         \
            else       DO_MFMA(0, ahi_, alo_, base_);                         \
        }                                                                     \
        if ((c) < 7) __syncthreads();                                         \
    } while (0)

    // prologue: stage chunk 0 + prefetch chunk-0 t=0,1 into pa; full drain once
    STAGEW(0, 0);
    pa0 = *(const f32x4*)(xrow);
    pa1 = *(const f32x4*)(xrow + 4);
    pa2 = *(const f32x4*)(xrow + 16);
    pa3 = *(const f32x4*)(xrow + 20);
    __syncthreads();

    CHUNK(0, pa0, pa1, pa2, pa3, pb0, pb1, pb2, pb3);
    CHUNK(1, pb0, pb1, pb2, pb3, pa0, pa1, pa2, pa3);
    CHUNK(2, pa0, pa1, pa2, pa3, pb0, pb1, pb2, pb3);
    CHUNK(3, pb0, pb1, pb2, pb3, pa0, pa1, pa2, pa3);
    CHUNK(4, pa0, pa1, pa2, pa3, pb0, pb1, pb2, pb3);
    CHUNK(5, pb0, pb1, pb2, pb3, pa0, pa1, pa2, pa3);
    CHUNK(6, pa0, pa1, pa2, pa3, pb0, pb1, pb2, pb3);
    CHUNK(7, pb0, pb1, pb2, pb3, pa0, pa1, pa2, pa3);

    // ---- epilogue (validated round-8 math) ----
    sum   += __shfl_xor(sum, 32);
    sumsq += __shfl_xor(sumsq, 32);
    float mu   = sum * (1.f / 1024.f);
    float var  = sumsq * (1.f / 1024.f) - mu * mu;
    float rstd = rsqrtf(var + LN_EPS);

    float uv[2], vv[2], g2v[2], b2v[2];
#pragma unroll
    for (int nt = 0; nt < 2; ++nt) {
        int bitc = nt * 32 + col;
        uv[nt] = u[bitc]; vv[nt] = v[bitc]; g2v[nt] = g2[bitc]; b2v[nt] = b2[bitc];
    }

    float ps0 = 0.f, ps1 = 0.f;
#pragma unroll
    for (int reg = 0; reg < 16; ++reg) {
        int r = (reg & 3) + 8 * (reg >> 2) + 4 * hi;   // row within wave, 0..31
        float mu_r = __shfl(mu, r);
        float rs_r = __shfl(rstd, r);
        float d0 = (aH0[0][reg] + aH1[0][reg]) + aM[0][reg] * (1.0f / 2048.0f);
        float d1 = (aH0[1][reg] + aH1[1][reg]) + aM[1][reg] * (1.0f / 2048.0f);
        float lg0 = rs_r * d0 - rs_r * mu_r * uv[0] + vv[0];
        float lg1 = rs_r * d1 - rs_r * mu_r * uv[1] + vv[1];
        float s1 = lg0 + lg1;
        float s2 = lg0 * lg0 + lg1 * lg1;
#pragma unroll
        for (int m = 1; m <= 16; m <<= 1) {
            s1 += __shfl_xor(s1, m);
            s2 += __shfl_xor(s2, m);
        }
        float mean = s1 * (1.f / 64.f);
        float va   = s2 * (1.f / 64.f) - mean * mean;
        float rs2  = rsqrtf(va + LN_EPS);
        float o0 = (lg0 - mean) * rs2 * g2v[0] + b2v[0];
        float o1 = (lg1 - mean) * rs2 * g2v[1] + b2v[1];
        size_t row = (size_t)(row_base + r);
        L[row * 64 + col]      = o0;
        L[row * 64 + 32 + col] = o1;
        ps0 += o0;
        ps1 += o1;
    }

    ps0 += __shfl_xor(ps0, 32);
    ps1 += __shfl_xor(ps1, 32);
    if (hi == 0) {
        P[(size_t)col * 2048        + blockIdx.x * 4 + wid] = ps0;
        P[(size_t)(32 + col) * 2048 + blockIdx.x * 4 + wid] = ps1;
    }
#undef STAGEW
#undef SB0
#undef DO_MFMA
#undef CHUNK
}

// ---------------- kernel 2: reduce column partials -> column means ----------------
__global__ void reduce_kernel(const float* __restrict__ P, float* __restrict__ cm) {
    int bit = blockIdx.x, t = threadIdx.x;
    float s = 0.f;
    for (int p = t; p < 2048; p += 256) s += P[(size_t)bit * 2048 + p];
    __shared__ float sh[256];
    sh[t] = s;
    __syncthreads();
    for (int off = 128; off > 0; off >>= 1) {
        if (t < off) sh[t] += sh[t + off];
        __syncthreads();
    }
    if (t == 0) cm[bit] = sh[0] * (1.f / (float)N_ROWS);
}

// ---------------- kernel 3: mean-center + fast sign-exact tanh + binarize ----------------
__global__ void final_kernel(const float* __restrict__ L, const float* __restrict__ cm,
                             float* __restrict__ out) {
    __shared__ float cms[64];
    if (threadIdx.x < 64) cms[threadIdx.x] = cm[threadIdx.x];
    __syncthreads();
    const f32x4* L4 = (const f32x4*)L;
    f32x4* H4 = (f32x4*)out;
    f32x4* B4 = (f32x4*)(out + (size_t)N_ROWS * NBIT);
    int total = N_ROWS * NBIT / 4;
    for (int i = blockIdx.x * blockDim.x + threadIdx.x; i < total;
         i += gridDim.x * blockDim.x) {
        f32x4 x = L4[i];
        int bb = (i & 15) * 4;
        f32x4 h, bo;
#pragma unroll
        for (int j = 0; j < 4; ++j) {
            float y  = 0.5f * (x[j] - cms[bb + j]);
            float y2 = y * y;
            float poly = y * fmaf(y2, fmaf(y2, 2.f / 15.f, -1.f / 3.f), 1.f);
            float e  = __expf(2.f * y);
            float ef = 1.f - 2.f / (e + 1.f);
            float hv = (fabsf(y) < 0.5f) ? poly : ef;
            h[j]  = hv;
            bo[j] = hv >= 0.f ? 1.f : -1.f;
        }
        __builtin_nontemporal_store(h, &H4[i]);
        __builtin_nontemporal_store(bo, &B4[i]);
    }
}

extern "C" void kernel_launch(void* const* d_in, const int* in_sizes, int n_in,
                              void* d_out, int out_size, void* d_ws, size_t ws_size,
                              hipStream_t stream) {
    (void)in_sizes; (void)n_in; (void)out_size; (void)ws_size;
    const float* X  = (const float*)d_in[0];
    const float* W  = (const float*)d_in[1];
    const float* bb = (const float*)d_in[2];
    const float* g1 = (const float*)d_in[3];
    const float* b1 = (const float*)d_in[4];
    const float* g2 = (const float*)d_in[5];
    const float* b2 = (const float*)d_in[6];

    char* ws = (char*)d_ws;
    _Float16* whi = (_Float16*)ws;                 // 128 KiB
    _Float16* wlo = (_Float16*)(ws + 131072);      // 128 KiB
    float* u  = (float*)(ws + 262144);             // 256 B
    float* v  = (float*)(ws + 266240);             // 256 B
    float* P  = (float*)(ws + 270336);             // 512 KiB (64*2048*4)
    float* cm = (float*)(ws + 270336 + 64 * 2048 * 4);

    float* out = (float*)d_out;
    float* L   = out + (size_t)N_ROWS * NBIT;      // reuse B-half of d_out as logit scratch

    prep_kernel<<<64, 256, 0, stream>>>(W, bb, g1, b1, whi, wlo, u, v);
    main_kernel<<<512, 256, 0, stream>>>(X, whi, wlo, u, v, g2, b2, L, P);
    reduce_kernel<<<64, 256, 0, stream>>>(P, cm);
    final_kernel<<<2048, 256, 0, stream>>>(L, cm, out);
}